// Round 14
// baseline (55.728 us; speedup 1.0000x reference)
//
#include <hip/hip_runtime.h>
#include <hip/hip_bf16.h>
#include <math.h>

#define NROW 8192
#define DIM  128
#define BT   128            // square tile
#define NT   (NROW / BT)    // 64
#define NBLK ((NT * (NT + 1)) / 2)   // 2080
#define NWR  (NBLK * 4)     // per-wave results = 8320

typedef __bf16 bf16x8 __attribute__((ext_vector_type(8)));
typedef float  f32x4  __attribute__((ext_vector_type(4)));

#define G2     369.3299304675746f   /* 256 * log2(e): logits in base-2 */
#define QPOS   (0.9375f * G2)       /* xp = G2*s^2 - 2*G2*s + QPOS      */
#define QNEG   (-0.0625f * G2)      /* xn = G2*t^2 + QNEG, t=max(s,-.25)*/
#define NEGBIG (-3.0e38f)
#define MSENT  (-4000.0f)           /* empty-class sentinel */

// ---- Kernel A: normalize rows -> bf16 ----
__global__ __launch_bounds__(256)
void prep_kernel(const float* __restrict__ f, __hip_bfloat16* __restrict__ fhi) {
    int row  = blockIdx.x * 4 + (threadIdx.x >> 6);
    int lane = threadIdx.x & 63;
    float2 v = ((const float2*)(f + (size_t)row * DIM))[lane];
    float ss = v.x * v.x + v.y * v.y;
    #pragma unroll
    for (int off = 32; off; off >>= 1) ss += __shfl_xor(ss, off, 64);
    float inv = 1.0f / fmaxf(sqrtf(ss), 1e-12f);
    __hip_bfloat162 hv;
    hv.x = __float2bfloat16(v.x * inv);
    hv.y = __float2bfloat16(v.y * inv);
    ((__hip_bfloat162*)(fhi + (size_t)row * DIM))[lane] = hv;
}

// ---- Kernel B: 128x128 tile, 4 waves x 64x64 quadrant (0.5 ds_read/MFMA) ----
__global__ __launch_bounds__(256, 2)
void sim_kernel(const __hip_bfloat16* __restrict__ fhi,
                const int* __restrict__ lab,
                float4* __restrict__ blockRes) {
    const int tid  = threadIdx.x;
    const int w    = tid >> 6;     // 0..3
    const int lane = tid & 63;
    const int lrow = lane & 15;
    const int lk   = lane >> 4;

    // triangular decode: bid -> (tr, tc), tc >= tr (64x64 tile grid)
    int bid = blockIdx.x;
    int tr = (int)((129.0f - sqrtf(16641.0f - 8.0f * (float)bid)) * 0.5f);
    while (tr > 0 && bid < tr * NT - (tr * (tr - 1)) / 2) --tr;
    while (bid >= (tr + 1) * NT - ((tr + 1) * tr) / 2) ++tr;
    const int tc = tr + (bid - (tr * NT - (tr * (tr - 1)) / 2));

    const int rowBase = tr * BT;
    const int colBase = tc * BT;
    const bool edge = (tr == tc);

    __shared__ __align__(16) char smem[64 * 1024];  // A[128][256B] + B[128][256B]
    __shared__ int labA[BT];
    __shared__ int labB[BT];
    char* As = smem;
    char* Bs = smem + 32 * 1024;

    if (tid < BT)            labA[tid] = lab[rowBase + tid];
    else if (tid < 2 * BT)   labB[tid - BT] = lab[colBase + (tid - BT)];

    const int rsub4 = lane >> 4;              // row within 4-row segment
    const int col16 = (lane & 15) << 4;       // 16B slot within 256B row

    // ---- stage 64KB: 64 x 1KB segments, 16 per wave ----
    #pragma unroll
    for (int t = 0; t < 16; ++t) {
        int seg = w * 16 + t;                 // 0..63
        int arr = seg >> 5;                   // 0:A 1:B
        int s32 = seg & 31;
        int row = s32 * 4 + rsub4;            // 0..127
        const char* g = (const char*)fhi
            + (size_t)((arr ? colBase : rowBase) + row) * 256
            + (col16 ^ ((row & 7) << 4));     // pre-swizzled source (rule 21)
        char* ldsb = (arr ? Bs : As) + s32 * 1024;
        __builtin_amdgcn_global_load_lds(
            (const __attribute__((address_space(1))) void*)g,
            (__attribute__((address_space(3))) void*)ldsb, 16, 0, 0);
    }

    f32x4 acc[4][4];
    #pragma unroll
    for (int mi = 0; mi < 4; ++mi)
        #pragma unroll
        for (int ni = 0; ni < 4; ++ni) acc[mi][ni] = (f32x4){0.f, 0.f, 0.f, 0.f};

    const int mrow0 = (w >> 1) * 64;   // 2x2 wave grid: 64x64 per wave
    const int ncol0 = (w & 1) * 64;

    __syncthreads();   // single barrier: drains all loads + label writes

    #pragma unroll
    for (int q = 0; q < 4; ++q) {
        const int kb = q * 64 + lk * 16;
        bf16x8 bfr[4];
        #pragma unroll
        for (int ni = 0; ni < 4; ++ni) {
            int rb = colBase ? (ncol0 + ni * 16 + lrow) : (ncol0 + ni * 16 + lrow);
            rb = ncol0 + ni * 16 + lrow;
            bfr[ni] = *(const bf16x8*)(Bs + rb * 256 + (kb ^ ((rb & 7) << 4)));
        }
        bf16x8 afr[4];
        #pragma unroll
        for (int mi = 0; mi < 4; ++mi) {
            int ra = mrow0 + mi * 16 + lrow;
            afr[mi] = *(const bf16x8*)(As + ra * 256 + (kb ^ ((ra & 7) << 4)));
        }
        #pragma unroll
        for (int mi = 0; mi < 4; ++mi)
            #pragma unroll
            for (int ni = 0; ni < 4; ++ni)
                acc[mi][ni] = __builtin_amdgcn_mfma_f32_16x16x32_bf16(
                    afr[mi], bfr[ni], acc[mi][ni], 0, 0, 0);
    }

    // ---- lean monotone epilogue ----
    int lbv[4];
    #pragma unroll
    for (int ni = 0; ni < 4; ++ni) lbv[ni] = labB[ncol0 + ni * 16 + lrow];
    int4 laR[4];
    #pragma unroll
    for (int mi = 0; mi < 4; ++mi)
        laR[mi] = *(const int4*)&labA[mrow0 + mi * 16 + lk * 4];

    float minp = 1e30f;    // min s over valid positives (xp decreasing in s)
    float mabs = -1.0f;    // max |t| over valid negatives

#define PASS_A(EDGEF)                                                          \
    _Pragma("unroll")                                                          \
    for (int mi = 0; mi < 4; ++mi) {                                           \
        const int la[4] = {laR[mi].x, laR[mi].y, laR[mi].z, laR[mi].w};        \
        _Pragma("unroll")                                                      \
        for (int ni = 0; ni < 4; ++ni) {                                       \
            _Pragma("unroll")                                                  \
            for (int r = 0; r < 4; ++r) {                                      \
                float s = acc[mi][ni][r];                                      \
                bool pos = (la[r] == lbv[ni]);                                 \
                float t = fmaxf(s, -0.25f);                                    \
                bool valid = true;                                             \
                if (EDGEF) {                                                   \
                    int il = mrow0 + mi * 16 + lk * 4 + r;                     \
                    int jl = ncol0 + ni * 16 + lrow;                           \
                    valid = (jl > il);                                         \
                    pos = pos && valid;                                        \
                }                                                              \
                float u = pos ? s : t;                                         \
                minp = fminf(minp, pos ? s : 1e30f);                           \
                bool nm = EDGEF ? (valid && !pos) : !pos;                      \
                mabs = fmaxf(mabs, nm ? fabsf(t) : -1.0f);                     \
                acc[mi][ni][r] = u;                                            \
            }                                                                  \
        }                                                                      \
    }
    if (edge) { PASS_A(true) } else { PASS_A(false) }
#undef PASS_A

    #pragma unroll
    for (int off = 32; off; off >>= 1) {
        minp = fminf(minp, __shfl_xor(minp, off, 64));
        mabs = fmaxf(mabs, __shfl_xor(mabs, off, 64));
    }
    const float Mp = (minp < 2.0f)
        ? fmaf(G2, minp * minp, fmaf(-2.0f * G2, minp, QPOS)) : MSENT;
    const float Mn = (mabs >= 0.0f) ? fmaf(G2, mabs * mabs, QNEG) : MSENT;
    const float qph = QPOS - Mp;
    const float qnh = QNEG - Mn;
    float sp = 0.f, sn = 0.f;

#define PASS_B(EDGEF)                                                          \
    _Pragma("unroll")                                                          \
    for (int mi = 0; mi < 4; ++mi) {                                           \
        const int la[4] = {laR[mi].x, laR[mi].y, laR[mi].z, laR[mi].w};        \
        _Pragma("unroll")                                                      \
        for (int ni = 0; ni < 4; ++ni) {                                       \
            _Pragma("unroll")                                                  \
            for (int r = 0; r < 4; ++r) {                                      \
                float u = acc[mi][ni][r];                                      \
                bool pos = (la[r] == lbv[ni]);                                 \
                float P  = pos ? (-2.0f * G2) : 0.0f;                          \
                float Qh = pos ? qph : qnh;                                    \
                float e = __builtin_amdgcn_exp2f(                              \
                              fmaf(G2, u * u, fmaf(P, u, Qh)));                \
                if (EDGEF) {                                                   \
                    int il = mrow0 + mi * 16 + lk * 4 + r;                     \
                    int jl = ncol0 + ni * 16 + lrow;                           \
                    e = (jl > il) ? e : 0.f;                                   \
                }                                                              \
                float ep = pos ? e : 0.f;                                      \
                sp += ep;                                                      \
                sn += (e - ep);                                                \
            }                                                                  \
        }                                                                      \
    }
    if (edge) { PASS_B(true) } else { PASS_B(false) }
#undef PASS_B

    #pragma unroll
    for (int off = 32; off; off >>= 1) {
        sp += __shfl_xor(sp, off, 64);
        sn += __shfl_xor(sn, off, 64);
    }
    if (lane == 0) blockRes[bid * 4 + w] = make_float4(Mp, sp, Mn, sn);
}

// ---- Kernel C: single-pass final (two-phase max/sum) + softplus ----
__global__ __launch_bounds__(1024)
void final_kernel(const float4* __restrict__ waveRes, float* __restrict__ out) {
    __shared__ float red[16][4];
    const int tid  = threadIdx.x;
    const int wv   = tid >> 6;
    const int lane = tid & 63;

    float4 e[9];
    int ne = 0;
    for (int i = tid; i < NWR; i += 1024) e[ne++] = waveRes[i];

    // phase A: global maxes (independent fmax, fully pipelined)
    float mp = NEGBIG, mn = NEGBIG;
    for (int k = 0; k < ne; ++k) {
        mp = fmaxf(mp, e[k].x);
        mn = fmaxf(mn, e[k].z);
    }
    #pragma unroll
    for (int off = 32; off; off >>= 1) {
        mp = fmaxf(mp, __shfl_xor(mp, off, 64));
        mn = fmaxf(mn, __shfl_xor(mn, off, 64));
    }
    if (lane == 0) { red[wv][0] = mp; red[wv][1] = mn; }
    __syncthreads();
    float MP = red[0][0], MN = red[0][1];
    #pragma unroll
    for (int q = 1; q < 16; ++q) {
        MP = fmaxf(MP, red[q][0]);
        MN = fmaxf(MN, red[q][1]);
    }

    // phase B: rescaled sums (independent exp2 + fma)
    float sp = 0.f, sn = 0.f;
    for (int k = 0; k < ne; ++k) {
        sp = fmaf(e[k].y, __builtin_amdgcn_exp2f(e[k].x - MP), sp);
        sn = fmaf(e[k].w, __builtin_amdgcn_exp2f(e[k].z - MN), sn);
    }
    #pragma unroll
    for (int off = 32; off; off >>= 1) {
        sp += __shfl_xor(sp, off, 64);
        sn += __shfl_xor(sn, off, 64);
    }
    __syncthreads();
    if (lane == 0) { red[wv][2] = sp; red[wv][3] = sn; }
    __syncthreads();
    if (tid == 0) {
        float Sp = 0.f, Sn = 0.f;
        #pragma unroll
        for (int q = 0; q < 16; ++q) { Sp += red[q][2]; Sn += red[q][3]; }
        const double LN2 = 0.6931471805599453;
        double lse_p = ((double)MP + log2((double)Sp)) * LN2;
        double lse_n = ((double)MN + log2((double)Sn)) * LN2;
        double xx = lse_p + lse_n;
        double r = (xx > 30.0) ? xx : log1p(exp(xx));
        out[0] = (float)r;
    }
}

extern "C" void kernel_launch(void* const* d_in, const int* in_sizes, int n_in,
                              void* d_out, int out_size, void* d_ws, size_t ws_size,
                              hipStream_t stream) {
    const float* f   = (const float*)d_in[0];
    const int*   lab = (const int*)d_in[1];
    float*  out      = (float*)d_out;

    __hip_bfloat16* fhi = (__hip_bfloat16*)d_ws;                   // 2 MB
    float4* blockRes = (float4*)((char*)d_ws + 4u * 1024 * 1024);  // 8320 float4

    prep_kernel<<<NROW / 4, 256, 0, stream>>>(f, fhi);
    sim_kernel<<<NBLK, 256, 0, stream>>>(fhi, lab, blockRes);
    final_kernel<<<1, 1024, 0, stream>>>(blockRes, out);
}

// Round 15
// 51.671 us; speedup vs baseline: 1.0785x; 1.0785x over previous
//
#include <hip/hip_runtime.h>
#include <hip/hip_bf16.h>
#include <math.h>

#define NROW 8192
#define DIM  128
#define BT   128            // square tile
#define NT   (NROW / BT)    // 64
#define NBLK ((NT * (NT + 1)) / 2)   // 2080

typedef __bf16 bf16x8 __attribute__((ext_vector_type(8)));
typedef float  f32x4  __attribute__((ext_vector_type(4)));

#define G2     369.3299304675746f   /* 256 * log2(e): logits in base-2 */
#define QPOS   (0.9375f * G2)       /* xp = G2*s^2 - 2*G2*s + QPOS      */
#define QNEG   (-0.0625f * G2)      /* xn = G2*t^2 + QNEG, t=max(s,-.25)*/
#define NEGBIG (-3.0e38f)
#define MSENT  (-4000.0f)           /* empty-class sentinel */
#define CSTR   32                   /* cursor stride: 1 counter / 128B  */

// ---- Kernel H: label histogram + exclusive prefix -> padded cursor ----
__global__ __launch_bounds__(256)
void hist_kernel(const int* __restrict__ lab, int* __restrict__ cursor) {
    __shared__ int h[4][64];
    const int tid  = threadIdx.x;
    const int w    = tid >> 6;
    const int lane = tid & 63;
    h[w][lane] = 0;
    __syncthreads();
    for (int i = tid; i < NROW; i += 256)
        atomicAdd(&h[w][lab[i]], 1);
    __syncthreads();
    if (tid < 64) {
        int tot = h[0][tid] + h[1][tid] + h[2][tid] + h[3][tid];
        int v = tot;
        #pragma unroll
        for (int off = 1; off < 64; off <<= 1) {
            int u = __shfl_up(v, off, 64);
            if (tid >= off) v += u;
        }
        cursor[tid * CSTR] = v - tot;   // exclusive prefix, cacheline-padded
    }
}

// ---- Kernel A: normalize rows -> bf16, scattered into label-sorted order ----
__global__ __launch_bounds__(256)
void prep_kernel(const float* __restrict__ f, const int* __restrict__ lab,
                 int* __restrict__ cursor,
                 __hip_bfloat16* __restrict__ fhi, int* __restrict__ labS) {
    int row  = blockIdx.x * 4 + (threadIdx.x >> 6);
    int lane = threadIdx.x & 63;
    float2 v = ((const float2*)(f + (size_t)row * DIM))[lane];
    float ss = v.x * v.x + v.y * v.y;
    #pragma unroll
    for (int off = 32; off; off >>= 1) ss += __shfl_xor(ss, off, 64);
    float inv = 1.0f / fmaxf(sqrtf(ss), 1e-12f);
    int l = lab[row];
    int dest = 0;
    if (lane == 0) dest = atomicAdd(&cursor[l * CSTR], 1);
    dest = __shfl(dest, 0, 64);
    __hip_bfloat162 hv;
    hv.x = __float2bfloat16(v.x * inv);
    hv.y = __float2bfloat16(v.y * inv);
    ((__hip_bfloat162*)(fhi + (size_t)dest * DIM))[lane] = hv;
    if (lane == 0) labS[dest] = l;
}

// ---- merge helper: (m,s) pairs represent s * 2^m ----
__device__ __forceinline__ void merge2(float& m, float& s, float mo, float so) {
    float M = fmaxf(m, mo);
    s = s * __builtin_amdgcn_exp2f(m - M) + so * __builtin_amdgcn_exp2f(mo - M);
    m = M;
}

// ---- Kernel B: 128x128 tile, 8 waves, one-shot stage, sorted purity split ----
__global__ __launch_bounds__(512, 4)
void sim_kernel(const __hip_bfloat16* __restrict__ fhi,
                const int* __restrict__ labS,
                float4* __restrict__ blockRes) {
    const int tid  = threadIdx.x;
    const int w    = tid >> 6;     // 0..7
    const int lane = tid & 63;
    const int lrow = lane & 15;
    const int lk   = lane >> 4;

    // triangular decode: bid -> (tr, tc), tc >= tr (64x64 tile grid)
    int bid = blockIdx.x;
    int tr = (int)((129.0f - sqrtf(16641.0f - 8.0f * (float)bid)) * 0.5f);
    while (tr > 0 && bid < tr * NT - (tr * (tr - 1)) / 2) --tr;
    while (bid >= (tr + 1) * NT - ((tr + 1) * tr) / 2) ++tr;
    const int tc = tr + (bid - (tr * NT - (tr * (tr - 1)) / 2));

    const int rowBase = tr * BT;
    const int colBase = tc * BT;
    const bool edge = (tr == tc);

    __shared__ __align__(16) char smem[64 * 1024];  // A[128][256B] + B[128][256B]
    __shared__ float red[8][4];
    char* As = smem;
    char* Bs = smem + 32 * 1024;

    const int rsub4 = lane >> 4;              // row within 4-row segment
    const int col16 = (lane & 15) << 4;       // 16B slot within 256B row

    // ---- stage 64KB: 64 x 1KB segments, 8 per wave ----
    #pragma unroll
    for (int t = 0; t < 8; ++t) {
        int seg = w * 8 + t;                  // 0..63
        int arr = seg >> 5;                   // 0:A 1:B
        int s32 = seg & 31;
        int row = s32 * 4 + rsub4;            // 0..127
        const char* g = (const char*)fhi
            + (size_t)((arr ? colBase : rowBase) + row) * 256
            + (col16 ^ ((row & 7) << 4));     // pre-swizzled source (rule 21)
        char* ldsb = (arr ? Bs : As) + s32 * 1024;
        __builtin_amdgcn_global_load_lds(
            (const __attribute__((address_space(1))) void*)g,
            (__attribute__((address_space(3))) void*)ldsb, 16, 0, 0);
    }

    // purity probe (uniform; sorted labels): pure-neg iff disjoint label ranges
    const bool pure = (!edge) && (labS[rowBase + BT - 1] != labS[colBase]);

    const int mrow0 = (w >> 2) * 64;   // 2x4 wave grid: 64x32 per wave
    const int ncol0 = (w & 3) * 32;

    // labels needed only for mixed tiles (uniform branch); issue before barrier
    int lbv[2];
    int4 laR[4];
    if (!pure) {
        #pragma unroll
        for (int ni = 0; ni < 2; ++ni) lbv[ni] = labS[colBase + ncol0 + ni * 16 + lrow];
        #pragma unroll
        for (int mi = 0; mi < 4; ++mi)
            laR[mi] = *(const int4*)&labS[rowBase + mrow0 + mi * 16 + lk * 4];
    }

    f32x4 acc[4][2];
    #pragma unroll
    for (int mi = 0; mi < 4; ++mi)
        #pragma unroll
        for (int ni = 0; ni < 2; ++ni) acc[mi][ni] = (f32x4){0.f, 0.f, 0.f, 0.f};

    __syncthreads();   // single barrier: drains all staging loads

    #pragma unroll
    for (int q = 0; q < 4; ++q) {
        const int kb = q * 64 + lk * 16;
        bf16x8 bfr[2];
        #pragma unroll
        for (int ni = 0; ni < 2; ++ni) {
            int rb = ncol0 + ni * 16 + lrow;
            bfr[ni] = *(const bf16x8*)(Bs + rb * 256 + (kb ^ ((rb & 7) << 4)));
        }
        #pragma unroll
        for (int mi = 0; mi < 4; ++mi) {
            int ra = mrow0 + mi * 16 + lrow;
            bf16x8 afr = *(const bf16x8*)(As + ra * 256 + (kb ^ ((ra & 7) << 4)));
            #pragma unroll
            for (int ni = 0; ni < 2; ++ni)
                acc[mi][ni] = __builtin_amdgcn_mfma_f32_16x16x32_bf16(
                    afr, bfr[ni], acc[mi][ni], 0, 0, 0);
        }
    }

    float Mp, Mn, sp, sn;
    if (pure) {
        // ======== PURE-NEGATIVE tile (~94%): ~9 ops + 1 exp2 per element =====
        float mx = 0.0f;
        #pragma unroll
        for (int mi = 0; mi < 4; ++mi)
            #pragma unroll
            for (int ni = 0; ni < 2; ++ni)
                #pragma unroll
                for (int r = 0; r < 4; ++r) {
                    float t = fmaxf(acc[mi][ni][r], -0.25f);
                    acc[mi][ni][r] = t;
                    mx = fmaxf(mx, fabsf(t));
                }
        #pragma unroll
        for (int off = 32; off; off >>= 1)
            mx = fmaxf(mx, __shfl_xor(mx, off, 64));
        const float zc = -G2 * mx * mx;
        sn = 0.f;
        #pragma unroll
        for (int mi = 0; mi < 4; ++mi)
            #pragma unroll
            for (int ni = 0; ni < 2; ++ni)
                #pragma unroll
                for (int r = 0; r < 4; ++r) {
                    float t = acc[mi][ni][r];
                    sn += __builtin_amdgcn_exp2f(fmaf(G2, t * t, zc));
                }
        #pragma unroll
        for (int off = 32; off; off >>= 1)
            sn += __shfl_xor(sn, off, 64);
        Mp = MSENT; sp = 0.f;
        Mn = fmaf(G2, mx * mx, QNEG);
    } else {
        // ======== MIXED / EDGE tile (~6%): lean monotone general path ========
        float minp = 1e30f;    // min s over valid positives
        float mabs = -1.0f;    // max |t| over valid negatives

#define PASS_A(EDGEF)                                                          \
    _Pragma("unroll")                                                          \
    for (int mi = 0; mi < 4; ++mi) {                                           \
        const int la[4] = {laR[mi].x, laR[mi].y, laR[mi].z, laR[mi].w};        \
        _Pragma("unroll")                                                      \
        for (int ni = 0; ni < 2; ++ni) {                                       \
            _Pragma("unroll")                                                  \
            for (int r = 0; r < 4; ++r) {                                      \
                float s = acc[mi][ni][r];                                      \
                bool pos = (la[r] == lbv[ni]);                                 \
                float t = fmaxf(s, -0.25f);                                    \
                bool valid = true;                                             \
                if (EDGEF) {                                                   \
                    int il = mrow0 + mi * 16 + lk * 4 + r;                     \
                    int jl = ncol0 + ni * 16 + lrow;                           \
                    valid = (jl > il);                                         \
                    pos = pos && valid;                                        \
                }                                                              \
                float u = pos ? s : t;                                         \
                minp = fminf(minp, pos ? s : 1e30f);                           \
                bool nm = EDGEF ? (valid && !pos) : !pos;                      \
                mabs = fmaxf(mabs, nm ? fabsf(t) : -1.0f);                     \
                acc[mi][ni][r] = u;                                            \
            }                                                                  \
        }                                                                      \
    }
        if (edge) { PASS_A(true) } else { PASS_A(false) }
#undef PASS_A

        #pragma unroll
        for (int off = 32; off; off >>= 1) {
            minp = fminf(minp, __shfl_xor(minp, off, 64));
            mabs = fmaxf(mabs, __shfl_xor(mabs, off, 64));
        }
        Mp = (minp < 2.0f)
            ? fmaf(G2, minp * minp, fmaf(-2.0f * G2, minp, QPOS)) : MSENT;
        Mn = (mabs >= 0.0f) ? fmaf(G2, mabs * mabs, QNEG) : MSENT;
        const float qph = QPOS - Mp;
        const float qnh = QNEG - Mn;
        sp = 0.f; sn = 0.f;

#define PASS_B(EDGEF)                                                          \
    _Pragma("unroll")                                                          \
    for (int mi = 0; mi < 4; ++mi) {                                           \
        const int la[4] = {laR[mi].x, laR[mi].y, laR[mi].z, laR[mi].w};        \
        _Pragma("unroll")                                                      \
        for (int ni = 0; ni < 2; ++ni) {                                       \
            _Pragma("unroll")                                                  \
            for (int r = 0; r < 4; ++r) {                                      \
                float u = acc[mi][ni][r];                                      \
                bool pos = (la[r] == lbv[ni]);                                 \
                float P  = pos ? (-2.0f * G2) : 0.0f;                          \
                float Qh = pos ? qph : qnh;                                    \
                float e = __builtin_amdgcn_exp2f(                              \
                              fmaf(G2, u * u, fmaf(P, u, Qh)));                \
                if (EDGEF) {                                                   \
                    int il = mrow0 + mi * 16 + lk * 4 + r;                     \
                    int jl = ncol0 + ni * 16 + lrow;                           \
                    e = (jl > il) ? e : 0.f;                                   \
                }                                                              \
                float ep = pos ? e : 0.f;                                      \
                sp += ep;                                                      \
                sn += (e - ep);                                                \
            }                                                                  \
        }                                                                      \
    }
        if (edge) { PASS_B(true) } else { PASS_B(false) }
#undef PASS_B

        #pragma unroll
        for (int off = 32; off; off >>= 1) {
            sp += __shfl_xor(sp, off, 64);
            sn += __shfl_xor(sn, off, 64);
        }
    }

    // ---- in-block merge: 8 wave results -> 1 float4 ----
    if (lane == 0) {
        red[w][0] = Mp; red[w][1] = sp; red[w][2] = Mn; red[w][3] = sn;
    }
    __syncthreads();
    if (tid == 0) {
        float mp = red[0][0], s_p = red[0][1], mn = red[0][2], s_n = red[0][3];
        #pragma unroll
        for (int q = 1; q < 8; ++q) {
            merge2(mp, s_p, red[q][0], red[q][1]);
            merge2(mn, s_n, red[q][2], red[q][3]);
        }
        blockRes[bid] = make_float4(mp, s_p, mn, s_n);
    }
}

// ---- Kernel C: single-pass final (two-phase max/sum) + softplus ----
__global__ __launch_bounds__(1024)
void final_kernel(const float4* __restrict__ blockRes, float* __restrict__ out) {
    __shared__ float red[16][4];
    const int tid  = threadIdx.x;
    const int wv   = tid >> 6;
    const int lane = tid & 63;

    float4 e[3];
    int ne = 0;
    for (int i = tid; i < NBLK; i += 1024) e[ne++] = blockRes[i];

    // phase A: global maxes
    float mp = NEGBIG, mn = NEGBIG;
    for (int k = 0; k < ne; ++k) {
        mp = fmaxf(mp, e[k].x);
        mn = fmaxf(mn, e[k].z);
    }
    #pragma unroll
    for (int off = 32; off; off >>= 1) {
        mp = fmaxf(mp, __shfl_xor(mp, off, 64));
        mn = fmaxf(mn, __shfl_xor(mn, off, 64));
    }
    if (lane == 0) { red[wv][0] = mp; red[wv][1] = mn; }
    __syncthreads();
    float MP = red[0][0], MN = red[0][1];
    #pragma unroll
    for (int q = 1; q < 16; ++q) {
        MP = fmaxf(MP, red[q][0]);
        MN = fmaxf(MN, red[q][1]);
    }

    // phase B: rescaled sums
    float sp = 0.f, sn = 0.f;
    for (int k = 0; k < ne; ++k) {
        sp = fmaf(e[k].y, __builtin_amdgcn_exp2f(e[k].x - MP), sp);
        sn = fmaf(e[k].w, __builtin_amdgcn_exp2f(e[k].z - MN), sn);
    }
    #pragma unroll
    for (int off = 32; off; off >>= 1) {
        sp += __shfl_xor(sp, off, 64);
        sn += __shfl_xor(sn, off, 64);
    }
    __syncthreads();
    if (lane == 0) { red[wv][2] = sp; red[wv][3] = sn; }
    __syncthreads();
    if (tid == 0) {
        float Sp = 0.f, Sn = 0.f;
        #pragma unroll
        for (int q = 0; q < 16; ++q) { Sp += red[q][2]; Sn += red[q][3]; }
        const double LN2 = 0.6931471805599453;
        double lse_p = ((double)MP + log2((double)Sp)) * LN2;
        double lse_n = ((double)MN + log2((double)Sn)) * LN2;
        double xx = lse_p + lse_n;
        double r = (xx > 30.0) ? xx : log1p(exp(xx));
        out[0] = (float)r;
    }
}

extern "C" void kernel_launch(void* const* d_in, const int* in_sizes, int n_in,
                              void* d_out, int out_size, void* d_ws, size_t ws_size,
                              hipStream_t stream) {
    const float* f   = (const float*)d_in[0];
    const int*   lab = (const int*)d_in[1];
    float*  out      = (float*)d_out;

    __hip_bfloat16* fhi = (__hip_bfloat16*)d_ws;                      // 2 MB
    int* labS    = (int*)((char*)d_ws + 2u * 1024 * 1024);            // 32 KB
    int* cursor  = (int*)((char*)d_ws + 3u * 1024 * 1024);            // 64*32 ints
    float4* blockRes = (float4*)((char*)d_ws + 4u * 1024 * 1024);     // 2080

    hist_kernel<<<1, 256, 0, stream>>>(lab, cursor);
    prep_kernel<<<NROW / 4, 256, 0, stream>>>(f, lab, cursor, fhi, labS);
    sim_kernel<<<NBLK, 512, 0, stream>>>(fhi, labS, blockRes);
    final_kernel<<<1, 1024, 0, stream>>>(blockRes, out);
}